// Round 1
// baseline (161653.455 us; speedup 1.0000x reference)
//
#include <hip/hip_runtime.h>
#include <cmath>

// Problem dims
#define BDIM 64
#define TLEN 512
#define IDIM 512
#define HDIM 1024
#define ODIM 512

__device__ __forceinline__ float sigmoidf_(float x) {
    return 1.0f / (1.0f + __expf(-x));
}

// One GRU layer step, k-split into S partial blocks per 16-wide j tile.
// grid = (HDIM/16, S) = (64, 4), block = 256 (lanes = b, waves = j-groups of 4).
// Last block per j-tile reduces partials + gate math + writes hnew.
// Partial layout: part[((s*4+v)*HDIM + j)*64 + b], v in {r, z, n_x, n_h}.
template<int XK>
__global__ __launch_bounds__(256)
void gru_step_kernel(const float* __restrict__ x, int xstride,
                     const float* __restrict__ Wih, const float* __restrict__ Whh,
                     const float* __restrict__ bih, const float* __restrict__ bhh,
                     const float* __restrict__ hprev, float* __restrict__ hnew,
                     float* __restrict__ part, int* __restrict__ cnt)
{
    constexpr int S  = 4;
    constexpr int KC = 128;
    __shared__ float sh[64 * KC];   // staged activations, XOR-swizzled at float4 granularity
    __shared__ int last_flag;

    const int tid  = threadIdx.x;
    const int lane = tid & 63;                                    // b
    const int wave = __builtin_amdgcn_readfirstlane(tid >> 6);    // provably wave-uniform
    const int jt   = blockIdx.x;       // 0..63
    const int s    = blockIdx.y;       // 0..S-1
    const int j0   = jt * 16 + wave * 4;

    float accr[4]  = {0.f, 0.f, 0.f, 0.f};
    float accz[4]  = {0.f, 0.f, 0.f, 0.f};
    float accnx[4] = {0.f, 0.f, 0.f, 0.f};
    float accnh[4] = {0.f, 0.f, 0.f, 0.f};

    const int swz = lane & 31;

    auto phase = [&](const float* __restrict__ in, int instride, int k0, int klen,
                     const float* __restrict__ W, int Kr,
                     float* __restrict__ ar, float* __restrict__ az,
                     float* __restrict__ an) {
        for (int kc = 0; kc < klen; kc += KC) {
            __syncthreads();
            // stage in[0..63][k0+kc .. +KC) -> sh, coalesced global reads
            #pragma unroll
            for (int l = 0; l < (64 * KC) / 256; ++l) {
                int idx = tid + l * 256;
                int bb  = idx >> 7;          // KC == 128
                int kk  = idx & (KC - 1);
                int u   = kk >> 2;
                int e   = kk & 3;
                sh[bb * KC + (((u ^ (bb & 31)) << 2) | e)] =
                    in[bb * instride + k0 + kc + kk];
            }
            __syncthreads();
            for (int k4 = 0; k4 < KC; k4 += 4) {
                // lane-varying activation (1 x ds_read_b128, conflict-free via swizzle)
                const float4 v = *(const float4*)&sh[lane * KC + (((k4 >> 2) ^ swz) << 2)];
                const int wk = k0 + kc + k4;
                #pragma unroll
                for (int jj = 0; jj < 4; ++jj) {
                    // wave-uniform weight rows -> scalar loads (SMEM pipe)
                    const float4 wr = *(const float4*)&W[(j0 + jj) * Kr + wk];
                    const float4 wz = *(const float4*)&W[(HDIM + j0 + jj) * Kr + wk];
                    const float4 wn = *(const float4*)&W[(2 * HDIM + j0 + jj) * Kr + wk];
                    ar[jj] += v.x * wr.x + v.y * wr.y + v.z * wr.z + v.w * wr.w;
                    az[jj] += v.x * wz.x + v.y * wz.y + v.z * wz.z + v.w * wz.w;
                    an[jj] += v.x * wn.x + v.y * wn.y + v.z * wn.z + v.w * wn.w;
                }
            }
        }
    };

    phase(x,     xstride, s * (XK / S),   XK / S,   Wih, XK,   accr, accz, accnx);
    phase(hprev, HDIM,    s * (HDIM / S), HDIM / S, Whh, HDIM, accr, accz, accnh);

    // write partials (coalesced: lane = b fastest)
    #pragma unroll
    for (int jj = 0; jj < 4; ++jj) {
        int j = j0 + jj;
        part[((s * 4 + 0) * HDIM + j) * 64 + lane] = accr[jj];
        part[((s * 4 + 1) * HDIM + j) * 64 + lane] = accz[jj];
        part[((s * 4 + 2) * HDIM + j) * 64 + lane] = accnx[jj];
        part[((s * 4 + 3) * HDIM + j) * 64 + lane] = accnh[jj];
    }
    __threadfence();
    __syncthreads();
    if (tid == 0) {
        int old = atomicAdd(&cnt[jt], 1);
        last_flag = (old == S - 1) ? 1 : 0;
    }
    __syncthreads();
    if (!last_flag) return;
    __threadfence();

    // last block for this j-tile: reduce k-split partials + gate math
    float hv[4];
    #pragma unroll
    for (int jj = 0; jj < 4; ++jj) {
        int j = j0 + jj;
        float r = 0.f, z = 0.f, nx = 0.f, nh = 0.f;
        #pragma unroll
        for (int ss = 0; ss < S; ++ss) {
            r  += part[((ss * 4 + 0) * HDIM + j) * 64 + lane];
            z  += part[((ss * 4 + 1) * HDIM + j) * 64 + lane];
            nx += part[((ss * 4 + 2) * HDIM + j) * 64 + lane];
            nh += part[((ss * 4 + 3) * HDIM + j) * 64 + lane];
        }
        r = sigmoidf_(r + bih[j] + bhh[j]);
        z = sigmoidf_(z + bih[HDIM + j] + bhh[HDIM + j]);
        // PyTorch GRU: n = tanh(W_in x + b_in + r * (W_hn h + b_hn))
        float n = tanhf(nx + bih[2 * HDIM + j] + r * (nh + bhh[2 * HDIM + j]));
        hv[jj] = (1.f - z) * n + z * hprev[lane * HDIM + j];
    }
    *(float4*)&hnew[lane * HDIM + j0] = make_float4(hv[0], hv[1], hv[2], hv[3]);
    if (tid == 0) cnt[jt] = 0;   // re-arm for next step
}

// Output projection: out[b][o] = h1 . Wout[o] + bout[o]
// grid = (ODIM/16, 8), block = 256.
__global__ __launch_bounds__(256)
void out_step_kernel(const float* __restrict__ hin,
                     const float* __restrict__ Wout, const float* __restrict__ bout,
                     float* __restrict__ outp,
                     float* __restrict__ part, int* __restrict__ cnt)
{
    constexpr int S  = 8;
    constexpr int KC = 128;
    __shared__ float sh[64 * KC];
    __shared__ int last_flag;

    const int tid  = threadIdx.x;
    const int lane = tid & 63;
    const int wave = __builtin_amdgcn_readfirstlane(tid >> 6);
    const int ot   = blockIdx.x;   // 0..31
    const int s    = blockIdx.y;   // 0..7
    const int o0   = ot * 16 + wave * 4;
    const int k0   = s * (HDIM / S);   // 128-wide k slice

    float acc[4] = {0.f, 0.f, 0.f, 0.f};

    #pragma unroll
    for (int l = 0; l < (64 * KC) / 256; ++l) {
        int idx = tid + l * 256;
        int bb  = idx >> 7;
        int kk  = idx & (KC - 1);
        int u   = kk >> 2;
        int e   = kk & 3;
        sh[bb * KC + (((u ^ (bb & 31)) << 2) | e)] = hin[bb * HDIM + k0 + kk];
    }
    __syncthreads();
    const int swz = lane & 31;
    for (int k4 = 0; k4 < KC; k4 += 4) {
        const float4 v = *(const float4*)&sh[lane * KC + (((k4 >> 2) ^ swz) << 2)];
        #pragma unroll
        for (int jj = 0; jj < 4; ++jj) {
            const float4 w = *(const float4*)&Wout[(o0 + jj) * HDIM + k0 + k4];
            acc[jj] += v.x * w.x + v.y * w.y + v.z * w.z + v.w * w.w;
        }
    }
    #pragma unroll
    for (int jj = 0; jj < 4; ++jj)
        part[(s * ODIM + o0 + jj) * 64 + lane] = acc[jj];

    __threadfence();
    __syncthreads();
    if (tid == 0) {
        int old = atomicAdd(&cnt[ot], 1);
        last_flag = (old == S - 1) ? 1 : 0;
    }
    __syncthreads();
    if (!last_flag) return;
    __threadfence();

    float ov[4];
    #pragma unroll
    for (int jj = 0; jj < 4; ++jj) {
        int o = o0 + jj;
        float a = bout[o];
        #pragma unroll
        for (int ss = 0; ss < S; ++ss)
            a += part[(ss * ODIM + o) * 64 + lane];
        ov[jj] = a;
    }
    *(float4*)&outp[lane * ODIM + o0] = make_float4(ov[0], ov[1], ov[2], ov[3]);
    if (tid == 0) cnt[ot] = 0;
}

__global__ void init_kernel(float* __restrict__ h0, float* __restrict__ h1,
                            int* __restrict__ cnt)
{
    int tid = blockIdx.x * blockDim.x + threadIdx.x;
    if (tid < BDIM * HDIM) {
        h0[tid] = 0.f;   // h0 read-buffer for t=0
        h1[tid] = 0.f;   // h1 read-buffer for t=0
    }
    if (tid < 96) cnt[tid] = 0;
}

extern "C" void kernel_launch(void* const* d_in, const int* in_sizes, int n_in,
                              void* d_out, int out_size, void* d_ws, size_t ws_size,
                              hipStream_t stream)
{
    const float* src  = (const float*)d_in[0];
    // d_in[1] = target, unused by the reference output
    const float* Wih0 = (const float*)d_in[2];
    const float* Whh0 = (const float*)d_in[3];
    const float* bih0 = (const float*)d_in[4];
    const float* bhh0 = (const float*)d_in[5];
    const float* Wih1 = (const float*)d_in[6];
    const float* Whh1 = (const float*)d_in[7];
    const float* bih1 = (const float*)d_in[8];
    const float* bhh1 = (const float*)d_in[9];
    const float* Wout = (const float*)d_in[10];
    const float* bout = (const float*)d_in[11];
    float* out = (float*)d_out;

    // ws layout (floats):
    //   h0 double buffer : 2 * 64*1024
    //   h1 double buffer : 2 * 64*1024
    //   layer partials   : 4(S) * 4(v) * 1024 * 64
    //   out partials     : 8(S) * 512 * 64
    //   counters (int)   : 96
    float* ws    = (float*)d_ws;
    float* h0    = ws;
    float* h1    = ws + 2 * BDIM * HDIM;
    float* partL = ws + 4 * BDIM * HDIM;
    float* partO = partL + 4 * 4 * HDIM * BDIM;
    int*   cnt   = (int*)(partO + 8 * ODIM * BDIM);
    int*   cntL  = cnt;
    int*   cntO  = cnt + 64;

    hipLaunchKernelGGL(init_kernel, dim3(256), dim3(256), 0, stream, h0, h1, cnt);

    for (int t = 0; t < TLEN; ++t) {
        const int rd = t & 1;
        const int wr = 1 - rd;
        const float* xt = src + t * IDIM;   // source[b][t][i], row stride T*I

        hipLaunchKernelGGL((gru_step_kernel<IDIM>), dim3(64, 4), dim3(256), 0, stream,
                           xt, TLEN * IDIM, Wih0, Whh0, bih0, bhh0,
                           h0 + rd * BDIM * HDIM, h0 + wr * BDIM * HDIM,
                           partL, cntL);

        hipLaunchKernelGGL((gru_step_kernel<HDIM>), dim3(64, 4), dim3(256), 0, stream,
                           h0 + wr * BDIM * HDIM, HDIM, Wih1, Whh1, bih1, bhh1,
                           h1 + rd * BDIM * HDIM, h1 + wr * BDIM * HDIM,
                           partL, cntL);

        hipLaunchKernelGGL(out_step_kernel, dim3(32, 8), dim3(256), 0, stream,
                           h1 + wr * BDIM * HDIM, Wout, bout, out + t * BDIM * ODIM,
                           partO, cntO);
    }
}